// Round 11
// baseline (43.872 us; speedup 1.0000x reference)
//
#include <hip/hip_runtime.h>
#include <hip/hip_fp16.h>
#include <hip/hip_bf16.h>

#define NN 256
#define AA 1024
#define JJ 4096          // B*C
#define OUTW 1152        // A + B

typedef __attribute__((ext_vector_type(8))) short short8v;
typedef __attribute__((ext_vector_type(4))) float floatx4;

__device__ __forceinline__ unsigned f2bf(float f) {
    __hip_bfloat16 h = __float2bfloat16(f);   // RNE hardware convert
    return (unsigned)*(unsigned short*)&h;
}
__device__ __forceinline__ short8v as8(uint4 v) {
    union { uint4 u; short8v s; } c; c.u = v; return c.s;
}

// ---------------------------------------------------------------------------
// cvt_copy: out[n][0:1024] = x[n]  AND  xb = bf16(x)   (r5-verified body)
// ---------------------------------------------------------------------------
__global__ __launch_bounds__(256) void cvt_copy(const float* __restrict__ x,
                                                float* __restrict__ out,
                                                unsigned short* __restrict__ xb) {
    const int row = blockIdx.x;
    const int t = threadIdx.x;
    float4 v = *(const float4*)&x[(size_t)row * AA + t * 4];
    *(float4*)&out[(size_t)row * OUTW + t * 4] = v;
    uint2 p;
    p.x = f2bf(v.x) | (f2bf(v.y) << 16);
    p.y = f2bf(v.z) | (f2bf(v.w) << 16);
    *(uint2*)&xb[(size_t)row * AA + t * 4] = p;
}

// ---------------------------------------------------------------------------
// fused: block (b = bid&127, h = bid>>7), 1024 thr (16 waves), grid 256.
// Phase A (GEMM M_b[256][32] = x @ T[:,b*32..+32)):
//   - consumer waves 0..7: wave cw owns rows 32cw..+32 (2 row-subtiles),
//     all 32 cols. A-fragments loaded DIRECTLY from bf16 xb (1 dwordx4 per
//     frag -- no LDS for A at all); B-frags from LDS; 8 MFMA/chunk.
//   - producer waves 8..15: stage T chunk (32 cols x 64 k, f32->bf16) into
//     the 4 KB double-buffered ts; prefetch distance 2 in registers.
//   - per chunk: 2 raw s_barriers + lgkmcnt(0) only (global loads stay in
//     flight across barriers; only LDS writes need the wait).
// Phase B: r10-verified pairwise, all 16 waves (128 n x 8 m-groups).
// Swizzle (rule 21): byte ^= ((row&7)<<4) identically on write and read.
// LDS: ts 8 KB + Mb 16 KB + red 4 KB = 28 KB.
// ---------------------------------------------------------------------------
__global__ __launch_bounds__(1024) void fused(const unsigned short* __restrict__ xb,
                                              const float* __restrict__ T,
                                              float* __restrict__ out) {
    __shared__ unsigned short ts[2][32 * 64];   // 4 KB per buffer
    __shared__ __half Mb[256][32];              // 16 KB
    __shared__ float red[8][128];               // 4 KB

    const int bid = blockIdx.x;
    const int b = bid & 127;
    const int h = bid >> 7;
    const int tid = threadIdx.x;
    const int lane = tid & 63;
    const int w = tid >> 6;                     // 0..15
    const bool prod = (w >= 8);

    // ---- producer setup (waves 8..15): 512 threads stage 2048 elems/chunk
    const int pid = tid & 511;
    const int pcol = pid & 31;                  // T col 0..31
    const int pkq = pid >> 5;                   // k-quad 0..15 (4 k each)
    const float* tp = T + (size_t)(pkq * 4) * JJ + b * 32 + pcol;
    const int pW = pcol * 128 + ((pkq * 8) ^ ((pcol & 7) << 4));

    struct Tp { float t0, t1, t2, t3; };
    Tp TA, TB;
    auto TLOAD = [&](Tp& S, int C) {
        const float* q = tp + (size_t)C * 64 * JJ;
        S.t0 = q[0]; S.t1 = q[JJ]; S.t2 = q[2 * JJ]; S.t3 = q[3 * JJ];
    };
    auto TSTAGE = [&](const Tp& S, int buf) {
        uint2 p;
        p.x = f2bf(S.t0) | (f2bf(S.t1) << 16);
        p.y = f2bf(S.t2) | (f2bf(S.t3) << 16);
        *(uint2*)((char*)ts[buf] + pW) = p;
    };

    // ---- consumer setup (waves 0..7): rows 32w..+32, cols 0..32
    const int rf = lane & 15;
    const int g = lane >> 4;
    const int fsw = (rf & 7) << 4;
    const int b0Row = rf * 128;                 // cols 0..15
    const int b1Row = (16 + rf) * 128;          // cols 16..31
    const int k0 = (g * 16) ^ fsw;              // ks=0 byte offset (r10-verified)
    const int k1 = (64 + g * 16) ^ fsw;         // ks=1

    const unsigned short* ar0 = xb + (size_t)(32 * w + rf) * AA + 8 * g;
    const unsigned short* ar1 = ar0 + 16 * AA;  // second row-subtile

    struct Ap { uint4 a00, a01, a10, a11; };    // a{rowsub}{ks}
    Ap PA, PB;
    auto ALOAD = [&](Ap& S, int C) {
        const unsigned short* p0 = ar0 + C * 64;
        const unsigned short* p1 = ar1 + C * 64;
        S.a00 = *(const uint4*)(p0);
        S.a01 = *(const uint4*)(p0 + 32);
        S.a10 = *(const uint4*)(p1);
        S.a11 = *(const uint4*)(p1 + 32);
    };

    floatx4 acc00 = {0.f, 0.f, 0.f, 0.f};
    floatx4 acc01 = {0.f, 0.f, 0.f, 0.f};
    floatx4 acc10 = {0.f, 0.f, 0.f, 0.f};
    floatx4 acc11 = {0.f, 0.f, 0.f, 0.f};

    auto COMP = [&](const Ap& S, int buf) {
        short8v b00 = *(const short8v*)((char*)ts[buf] + b0Row + k0);
        short8v b10 = *(const short8v*)((char*)ts[buf] + b1Row + k0);
        acc00 = __builtin_amdgcn_mfma_f32_16x16x32_bf16(as8(S.a00), b00, acc00, 0, 0, 0);
        acc01 = __builtin_amdgcn_mfma_f32_16x16x32_bf16(as8(S.a00), b10, acc01, 0, 0, 0);
        acc10 = __builtin_amdgcn_mfma_f32_16x16x32_bf16(as8(S.a10), b00, acc10, 0, 0, 0);
        acc11 = __builtin_amdgcn_mfma_f32_16x16x32_bf16(as8(S.a10), b10, acc11, 0, 0, 0);
        short8v b01 = *(const short8v*)((char*)ts[buf] + b0Row + k1);
        short8v b11 = *(const short8v*)((char*)ts[buf] + b1Row + k1);
        acc00 = __builtin_amdgcn_mfma_f32_16x16x32_bf16(as8(S.a01), b01, acc00, 0, 0, 0);
        acc01 = __builtin_amdgcn_mfma_f32_16x16x32_bf16(as8(S.a01), b11, acc01, 0, 0, 0);
        acc10 = __builtin_amdgcn_mfma_f32_16x16x32_bf16(as8(S.a11), b01, acc10, 0, 0, 0);
        acc11 = __builtin_amdgcn_mfma_f32_16x16x32_bf16(as8(S.a11), b11, acc11, 0, 0, 0);
    };

    // ---- prologue ----
    if (prod) { TLOAD(TA, 0); TLOAD(TB, 1); }
    else      { ALOAD(PA, 0); }

#pragma unroll 1
    for (int c = 0; c < 16; c += 2) {
        // even chunk c -> buf 0, set A
        __builtin_amdgcn_s_barrier();           // buf0 free (comp(c-2) done)
        if (prod) {
            TSTAGE(TA, 0);
            if (c + 2 < 16) TLOAD(TA, c + 2);
        } else {
            if (c + 1 < 16) ALOAD(PB, c + 1);
        }
        asm volatile("s_waitcnt lgkmcnt(0)" ::: "memory");
        __builtin_amdgcn_sched_barrier(0);
        __builtin_amdgcn_s_barrier();           // staged data visible
        if (!prod) COMP(PA, 0);

        // odd chunk c+1 -> buf 1, set B
        __builtin_amdgcn_s_barrier();
        if (prod) {
            TSTAGE(TB, 1);
            if (c + 3 < 16) TLOAD(TB, c + 3);
        } else {
            if (c + 2 < 16) ALOAD(PA, c + 2);
        }
        asm volatile("s_waitcnt lgkmcnt(0)" ::: "memory");
        __builtin_amdgcn_sched_barrier(0);
        __builtin_amdgcn_s_barrier();
        if (!prod) COMP(PB, 1);
    }

    // ---- M_b -> LDS (C/D: col = lane&15, row = (lane>>4)*4 + reg) ----
    if (!prod) {
        const int r0 = 32 * w + 4 * g;
#pragma unroll
        for (int r = 0; r < 4; ++r) {
            Mb[r0 + r][rf] = __float2half(acc00[r]);
            Mb[r0 + r][16 + rf] = __float2half(acc01[r]);
            Mb[r0 + 16 + r][rf] = __float2half(acc10[r]);
            Mb[r0 + 16 + r][16 + rf] = __float2half(acc11[r]);
        }
    }
    __syncthreads();

    // ---- phase B: pairwise (r10-verified). 1024 thr = 128 n x 8 m-groups --
    const int nl = tid & 127;
    const int mq = tid >> 7;                    // uniform per wave-pair
    const int n = h * 128 + nl;

    union u4h { uint4 u; __half2 hh[4]; };
    u4h mv[4];
#pragma unroll
    for (int i = 0; i < 4; ++i) mv[i].u = *(const uint4*)&Mb[n][i * 8];

    float o = 0.f;
    const int m0 = mq * 32;
#pragma unroll 4
    for (int m = m0; m < m0 + 32; ++m) {
        u4h rv[4];
#pragma unroll
        for (int i = 0; i < 4; ++i) rv[i].u = *(const uint4*)&Mb[m][i * 8];
        __half2 a0 = __habs2(__hsub2(mv[0].hh[0], rv[0].hh[0]));
        __half2 a1 = __habs2(__hsub2(mv[0].hh[1], rv[0].hh[1]));
        __half2 a2 = __habs2(__hsub2(mv[0].hh[2], rv[0].hh[2]));
        __half2 a3 = __habs2(__hsub2(mv[0].hh[3], rv[0].hh[3]));
#pragma unroll
        for (int i = 1; i < 4; ++i) {
            a0 = __hadd2(a0, __habs2(__hsub2(mv[i].hh[0], rv[i].hh[0])));
            a1 = __hadd2(a1, __habs2(__hsub2(mv[i].hh[1], rv[i].hh[1])));
            a2 = __hadd2(a2, __habs2(__hsub2(mv[i].hh[2], rv[i].hh[2])));
            a3 = __hadd2(a3, __habs2(__hsub2(mv[i].hh[3], rv[i].hh[3])));
        }
        __half2 s = __hadd2(__hadd2(a0, a1), __hadd2(a2, a3));
        float2 lf = __half22float2(s);
        o += __expf(-(lf.x + lf.y));
    }

    red[mq][nl] = o;
    __syncthreads();
    if (tid < 128) {
        float s = 0.f;
#pragma unroll
        for (int q2 = 0; q2 < 8; ++q2) s += red[q2][tid];
        out[(size_t)(h * 128 + tid) * OUTW + AA + b] = s;
    }
}

// ===========================================================================
extern "C" void kernel_launch(void* const* d_in, const int* in_sizes, int n_in,
                              void* d_out, int out_size, void* d_ws, size_t ws_size,
                              hipStream_t stream) {
    const float* x = (const float*)d_in[0];
    const float* T = (const float*)d_in[1];
    float* out = (float*)d_out;
    unsigned short* xb = (unsigned short*)d_ws;   // 512 KB

    cvt_copy<<<NN, 256, 0, stream>>>(x, out, xb);
    fused<<<256, 1024, 0, stream>>>(xb, T, out);
}

// Round 12
// 43.672 us; speedup vs baseline: 1.0046x; 1.0046x over previous
//
#include <hip/hip_runtime.h>
#include <hip/hip_fp16.h>
#include <hip/hip_bf16.h>

#define NN 256
#define AA 1024
#define JJ 4096          // B*C
#define OUTW 1152        // A + B

typedef __attribute__((ext_vector_type(8))) short short8v;
typedef __attribute__((ext_vector_type(4))) float floatx4;

__device__ __forceinline__ unsigned f2bf(float f) {
    __hip_bfloat16 h = __float2bfloat16(f);   // RNE; compiler lowers well (m240)
    return (unsigned)*(unsigned short*)&h;
}
__device__ __forceinline__ short8v as8(uint4 v) {
    union { uint4 u; short8v s; } c; c.u = v; return c.s;
}

// ---------------------------------------------------------------------------
// cvt_copy: out[n][0:1024] = x[n]  AND  xb = bf16(x)   (r5-verified body)
// ---------------------------------------------------------------------------
__global__ __launch_bounds__(256) void cvt_copy(const float* __restrict__ x,
                                                float* __restrict__ out,
                                                unsigned short* __restrict__ xb) {
    const int row = blockIdx.x;
    const int t = threadIdx.x;
    float4 v = *(const float4*)&x[(size_t)row * AA + t * 4];
    *(float4*)&out[(size_t)row * OUTW + t * 4] = v;
    uint2 p;
    p.x = f2bf(v.x) | (f2bf(v.y) << 16);
    p.y = f2bf(v.z) | (f2bf(v.w) << 16);
    *(uint2*)&xb[(size_t)row * AA + t * 4] = p;
}

// ---------------------------------------------------------------------------
// fused: block (b = bid&127, h = bid>>7), 1024 thr (16 waves), grid 256.
// Phase A: M_b[256][32] = x @ T[:,b*32..+32), bf16 MFMA 16x16x32.
//   A-fragments DIRECT from bf16 xb (L2-resident; wave reads 16 rows x 64 B
//   contiguous -- coalesced; NO x LDS staging at all). Only T staged in LDS
//   (4 KB double-buffered; 2 f32 loads + 1 ds_write dword per thread/chunk,
//   dist-2 register prefetch). All 16 waves compute (wave w = rows 16w..+16,
//   cols 0..32): 4 ds_read_b128 + 4 MFMA per chunk. Raw s_barrier +
//   lgkmcnt(0)-only between stage and compute (global loads stay in flight).
//   ts swizzle: byte = col*128 + (kbyte ^ ((col&7)<<4)) write+read (rule 21).
// Phase B: pairwise o[n][b] = sum_m exp(-L1(M_b[n],M_b[m])), n in h-half.
//   Thread = (np = tid&31, mg = tid>>5): 4 n rows {h*128+np+32r} in regs,
//   8 m each -> rv LDS reads cut 4x vs r10; wave spans 2 mg -> free 2-addr
//   broadcast (m136). Mb unit-swizzle byte = row*64 + (colb^(((row>>1)&3)<<4))
//   on write AND read -> mv init reads spread 8 words/bank (conflict-free).
// LDS: ts 8 KB + Mb 16 KB + red 16 KB = 40 KB.
// ---------------------------------------------------------------------------
__global__ __launch_bounds__(1024) void fused(const unsigned short* __restrict__ xb,
                                              const float* __restrict__ T,
                                              float* __restrict__ out) {
    __shared__ unsigned short ts[2][32 * 64];     // 4 KB each
    __shared__ __align__(16) char mb[256 * 64];   // Mb f16, swizzled, 16 KB
    __shared__ float red[32][128];                // 16 KB

    const int bid = blockIdx.x;
    const int b = bid & 127;
    const int h = bid >> 7;
    const int tid = threadIdx.x;
    const int lane = tid & 63;
    const int w = tid >> 6;                       // 0..15

    // ---- T staging assignment: 2 k x 1 col per thread ----
    const int pcol = tid & 31;
    const int pk2 = tid >> 5;                     // 0..31 (k-pair index)
    const float* tp = T + (size_t)(pk2 * 2) * JJ + b * 32 + pcol;
    const int pW = pcol * 128 + ((pk2 * 4) ^ ((pcol & 7) << 4));

    float tA0, tA1, tB0, tB1;
    auto TLOADA = [&](int C) { const float* q = tp + (size_t)C * 64 * JJ; tA0 = q[0]; tA1 = q[JJ]; };
    auto TLOADB = [&](int C) { const float* q = tp + (size_t)C * 64 * JJ; tB0 = q[0]; tB1 = q[JJ]; };

    // ---- compute assignment: wave w -> rows 16w..+16, cols 0..32 ----
    const int rf = lane & 15;
    const int g = lane >> 4;
    const int fsw = (rf & 7) << 4;
    const unsigned short* ap = xb + (size_t)(16 * w + rf) * AA + g * 8;
    const int b0r = rf * 128;
    const int b1r = (16 + rf) * 128;
    const int k0 = (g * 16) ^ fsw;
    const int k1 = (64 + g * 16) ^ fsw;

    struct Ap { uint4 a0, a1; };
    Ap PA, PB;
    auto ALOADA = [&](int C) { PA.a0 = *(const uint4*)(ap + C * 64); PA.a1 = *(const uint4*)(ap + C * 64 + 32); };
    auto ALOADB = [&](int C) { PB.a0 = *(const uint4*)(ap + C * 64); PB.a1 = *(const uint4*)(ap + C * 64 + 32); };

    floatx4 acc0 = {0.f, 0.f, 0.f, 0.f};
    floatx4 acc1 = {0.f, 0.f, 0.f, 0.f};

    auto COMP = [&](const Ap& S, int buf) {
        short8v b00 = *(const short8v*)((char*)ts[buf] + b0r + k0);
        short8v b10 = *(const short8v*)((char*)ts[buf] + b1r + k0);
        acc0 = __builtin_amdgcn_mfma_f32_16x16x32_bf16(as8(S.a0), b00, acc0, 0, 0, 0);
        acc1 = __builtin_amdgcn_mfma_f32_16x16x32_bf16(as8(S.a0), b10, acc1, 0, 0, 0);
        short8v b01 = *(const short8v*)((char*)ts[buf] + b0r + k1);
        short8v b11 = *(const short8v*)((char*)ts[buf] + b1r + k1);
        acc0 = __builtin_amdgcn_mfma_f32_16x16x32_bf16(as8(S.a1), b01, acc0, 0, 0, 0);
        acc1 = __builtin_amdgcn_mfma_f32_16x16x32_bf16(as8(S.a1), b11, acc1, 0, 0, 0);
    };

    // ---- prologue ----
    TLOADA(0); TLOADB(1); ALOADA(0);

#pragma unroll 1
    for (int c = 0; c < 16; c += 2) {
        __builtin_amdgcn_s_barrier();             // buf0 free
        *(unsigned*)((char*)ts[0] + pW) = f2bf(tA0) | (f2bf(tA1) << 16);
        if (c + 2 < 16) TLOADA(c + 2);
        ALOADB(c + 1);
        asm volatile("s_waitcnt lgkmcnt(0)" ::: "memory");
        __builtin_amdgcn_sched_barrier(0);
        __builtin_amdgcn_s_barrier();             // buf0 visible
        COMP(PA, 0);

        __builtin_amdgcn_s_barrier();             // buf1 free
        *(unsigned*)((char*)ts[1] + pW) = f2bf(tB0) | (f2bf(tB1) << 16);
        if (c + 3 < 16) TLOADB(c + 3);
        if (c + 2 < 16) ALOADA(c + 2);
        asm volatile("s_waitcnt lgkmcnt(0)" ::: "memory");
        __builtin_amdgcn_sched_barrier(0);
        __builtin_amdgcn_s_barrier();             // buf1 visible
        COMP(PB, 1);
    }

    // ---- epilogue A -> Mb (C/D: col = lane&15, row = g*4 + reg) ----
#pragma unroll
    for (int r = 0; r < 4; ++r) {
        const int row = 16 * w + 4 * g + r;
        const int sw = ((row >> 1) & 3) << 4;
        *(__half*)(mb + row * 64 + ((2 * rf) ^ sw)) = __float2half(acc0[r]);
        *(__half*)(mb + row * 64 + ((32 + 2 * rf) ^ sw)) = __float2half(acc1[r]);
    }
    __syncthreads();

    // ---- phase B ----
    const int np = tid & 31;
    const int mg = tid >> 5;                      // 0..31

    union u4h { uint4 u; __half2 hh[4]; };
    u4h mv[4][4];
#pragma unroll
    for (int rr = 0; rr < 4; ++rr) {
        const int row = h * 128 + np + 32 * rr;
        const int sw = ((row >> 1) & 3) << 4;
#pragma unroll
        for (int i = 0; i < 4; ++i)
            mv[rr][i].u = *(const uint4*)(mb + row * 64 + ((i * 16) ^ sw));
    }

    float o0 = 0.f, o1 = 0.f, o2 = 0.f, o3 = 0.f;
    const int m0 = mg * 8;
#pragma unroll 2
    for (int m = m0; m < m0 + 8; ++m) {
        const int sw = ((m >> 1) & 3) << 4;
        u4h rv[4];
#pragma unroll
        for (int i = 0; i < 4; ++i)
            rv[i].u = *(const uint4*)(mb + m * 64 + ((i * 16) ^ sw));
#pragma unroll
        for (int rr = 0; rr < 4; ++rr) {
            __half2 a0 = __habs2(__hsub2(mv[rr][0].hh[0], rv[0].hh[0]));
            __half2 a1 = __habs2(__hsub2(mv[rr][0].hh[1], rv[0].hh[1]));
            __half2 a2 = __habs2(__hsub2(mv[rr][0].hh[2], rv[0].hh[2]));
            __half2 a3 = __habs2(__hsub2(mv[rr][0].hh[3], rv[0].hh[3]));
#pragma unroll
            for (int i = 1; i < 4; ++i) {
                a0 = __hadd2(a0, __habs2(__hsub2(mv[rr][i].hh[0], rv[i].hh[0])));
                a1 = __hadd2(a1, __habs2(__hsub2(mv[rr][i].hh[1], rv[i].hh[1])));
                a2 = __hadd2(a2, __habs2(__hsub2(mv[rr][i].hh[2], rv[i].hh[2])));
                a3 = __hadd2(a3, __habs2(__hsub2(mv[rr][i].hh[3], rv[i].hh[3])));
            }
            __half2 s = __hadd2(__hadd2(a0, a1), __hadd2(a2, a3));
            float2 lf = __half22float2(s);
            const float e = __expf(-(lf.x + lf.y));
            if (rr == 0) o0 += e;
            else if (rr == 1) o1 += e;
            else if (rr == 2) o2 += e;
            else o3 += e;
        }
    }

    red[mg][np] = o0;
    red[mg][np + 32] = o1;
    red[mg][np + 64] = o2;
    red[mg][np + 96] = o3;
    __syncthreads();
    if (tid < 128) {
        float s = 0.f;
#pragma unroll
        for (int q2 = 0; q2 < 32; ++q2) s += red[q2][tid];
        out[(size_t)(h * 128 + tid) * OUTW + AA + b] = s;
    }
}

// ===========================================================================
extern "C" void kernel_launch(void* const* d_in, const int* in_sizes, int n_in,
                              void* d_out, int out_size, void* d_ws, size_t ws_size,
                              hipStream_t stream) {
    const float* x = (const float*)d_in[0];
    const float* T = (const float*)d_in[1];
    float* out = (float*)d_out;
    unsigned short* xb = (unsigned short*)d_ws;   // 512 KB

    cvt_copy<<<NN, 256, 0, stream>>>(x, out, xb);
    fused<<<256, 1024, 0, stream>>>(xb, T, out);
}